// Round 4
// baseline (3916.909 us; speedup 1.0000x reference)
//
#include <hip/hip_runtime.h>

#define N_ENT 50000
#define H 128
#define NREL 460
#define T_STEPS 8
#define NEDGE 600000
#define SLOPE 0.22916666666666666f
#define NBUK 391  // ceil(N_ENT/128)

typedef __attribute__((ext_vector_type(8))) short bf16x8;
typedef __attribute__((ext_vector_type(4))) float f32x4;
typedef unsigned short u16;
typedef unsigned int u32;
typedef unsigned long long u64;

__device__ __forceinline__ float b2f(u16 u) {
  union { u32 i; float f; } v; v.i = ((u32)u) << 16; return v.f;
}
__device__ __forceinline__ u16 f2b(float f) {
  union { float f; u32 i; } v; v.f = f;
  return (u16)((v.i + 0x7FFFu + ((v.i >> 16) & 1u)) >> 16);
}
__device__ __forceinline__ float wave_sum(float v) {
#pragma unroll
  for (int off = 32; off > 0; off >>= 1) v += __shfl_xor(v, off, 64);
  return v;
}

// ---------- weight prep: bf16 transposed [n][k], 5 matrices ----------
__global__ void convw_kernel(const float* __restrict__ wn, const float* __restrict__ wl,
                             const float* __restrict__ tg, u16* __restrict__ wbt) {
  int m = blockIdx.x >> 6;
  int f = ((blockIdx.x & 63) << 8) + threadIdx.x;
  int n = f >> 7, k = f & 127;
  const float* src;
  switch (m) {
    case 0: src = wn; break;          // w_neigh[0]
    case 1: src = wl; break;          // w_loop[0]
    case 2: src = wn + 16384; break;  // w_neigh[1]
    case 3: src = wl + 16384; break;  // w_loop[1]
    default: src = tg; break;         // tg_w
  }
  wbt[m * 16384 + n * 128 + k] = f2b(src[k * 128 + n]);
}

// rel table f32 -> bf16 (not transposed)
__global__ void convrel_kernel(const float* __restrict__ rel, u16* __restrict__ relb) {
  int i = blockIdx.x * 256 + threadIdx.x;  // grid 230*256 == 58880 exactly
  relb[i] = f2b(rel[i]);
}

// ---------- h0 = l2norm(emb_ent), f32 + bf16 ----------
__global__ void l2norm_kernel(const float* __restrict__ in, float* __restrict__ out,
                              u16* __restrict__ outb) {
  int row = blockIdx.x * 4 + (threadIdx.x >> 6);
  int lane = threadIdx.x & 63;
  size_t base = (size_t)row * H;
  float2 v = ((const float2*)(in + base))[lane];
  float ss = wave_sum(v.x * v.x + v.y * v.y);
  float inv = 1.0f / fmaxf(sqrtf(ss), 1e-12f);
  float2 o = {v.x * inv, v.y * inv};
  ((float2*)(out + base))[lane] = o;
  ushort2 ob; ob.x = f2b(o.x); ob.y = f2b(o.y);
  ((ushort2*)(outb + base))[lane] = ob;
}

// ---------- bucketed CSR build ----------
// per-block LDS histogram of dst>>7, flushed once
__global__ __launch_bounds__(256) void bucket_count(const int* __restrict__ dst,
                                                    int* __restrict__ bcnt) {
  int t = blockIdx.y;
  __shared__ int lc[NBUK];
  for (int j = threadIdx.x; j < NBUK; j += 256) lc[j] = 0;
  __syncthreads();
  for (int i = blockIdx.x * 256 + threadIdx.x; i < NEDGE; i += 64 * 256)
    atomicAdd(&lc[dst[(size_t)t * NEDGE + i] >> 7], 1);
  __syncthreads();
  for (int j = threadIdx.x; j < NBUK; j += 256)
    if (lc[j]) atomicAdd(&bcnt[t * NBUK + j], lc[j]);
}

// exclusive scan of 391 bucket counts per timestep; bstart + working cursor copy
__global__ __launch_bounds__(512) void bucket_scan(const int* __restrict__ bcnt,
                                                   int* __restrict__ bstart,
                                                   int* __restrict__ curA) {
  int t = blockIdx.x, tid = threadIdx.x;
  __shared__ int s[512];
  int v = (tid < NBUK) ? bcnt[t * NBUK + tid] : 0;
  s[tid] = v;
  __syncthreads();
  for (int off = 1; off < 512; off <<= 1) {
    int u = (tid >= off) ? s[tid - off] : 0;
    __syncthreads();
    s[tid] += u;
    __syncthreads();
  }
  if (tid < NBUK) {
    int ex = s[tid] - v;
    bstart[t * NBUK + tid] = ex;
    curA[t * NBUK + tid] = ex;
  }
}

// pass A: scatter edges to bucket regions (8B entries, dense sequential writes)
__global__ void passA_kernel(const int* __restrict__ src, const int* __restrict__ dst,
                             const int* __restrict__ ety, int* curA,
                             u64* __restrict__ tmp, int t) {
  int i = blockIdx.x * 256 + threadIdx.x;
  if (i < NEDGE) {
    size_t o = (size_t)t * NEDGE + i;
    int d = dst[o];
    int pos = atomicAdd(&curA[t * NBUK + (d >> 7)], 1);
    tmp[pos] = ((u64)d << 32) | (u32)src[o] | ((u32)ety[o] << 17);
  }
}

// pass B: one block per bucket; per-dst counts+scan in LDS, write rp ends,
// scatter final 4B entries within the bucket's small window
__global__ __launch_bounds__(256) void passB_kernel(const u64* __restrict__ tmp,
                                                    const int* __restrict__ bstart,
                                                    int* __restrict__ rp,
                                                    u32* __restrict__ edges, int t) {
  int b = blockIdx.x, tid = threadIdx.x;
  int start = bstart[t * NBUK + b];
  int end = (b + 1 < NBUK) ? bstart[t * NBUK + b + 1] : NEDGE;
  __shared__ int cnt[128], scn[128], cur[128];
  if (tid < 128) cnt[tid] = 0;
  __syncthreads();
  for (int i = start + tid; i < end; i += 256)
    atomicAdd(&cnt[(int)((tmp[i] >> 32) & 127)], 1);
  __syncthreads();
  if (tid < 128) scn[tid] = cnt[tid];
  __syncthreads();
  for (int off = 1; off < 128; off <<= 1) {
    int u = (tid < 128 && tid >= off) ? scn[tid - off] : 0;
    __syncthreads();
    if (tid < 128) scn[tid] += u;
    __syncthreads();
  }
  if (tid < 128) {
    int rs = start + scn[tid] - cnt[tid];
    cur[tid] = rs;
    int gd = (b << 7) + tid;
    if (gd < N_ENT) rp[t * N_ENT + gd] = rs + cnt[tid];  // end-of-row semantics
  }
  __syncthreads();
  for (int i = start + tid; i < end; i += 256) {
    u64 e = tmp[i];
    int p = atomicAdd(&cur[(int)((e >> 32) & 127)], 1);
    edges[(size_t)t * NEDGE + p] = (u32)e;
  }
}

// ---------- agg[d] = (sum h[src]+rel[ty]) / max(deg,1), bf16 in/out ----------
__global__ __launch_bounds__(256) void gather_kernel(const u16* __restrict__ hb,
                                                     const u16* __restrict__ relb,
                                                     const int* __restrict__ rp,
                                                     const u32* __restrict__ edges,
                                                     u16* __restrict__ aggb) {
  int d = blockIdx.x * 8 + (threadIdx.x >> 5);
  int q = threadIdx.x & 31;
  int start = d ? rp[d - 1] : 0, end = rp[d];
  float a0 = 0.f, a1 = 0.f, a2 = 0.f, a3 = 0.f;
  int i = start;
  for (; i + 2 <= end; i += 2) {
    u32 e0 = edges[i], e1 = edges[i + 1];
    ushort4 h0 = *(const ushort4*)(hb + (size_t)(e0 & 0x1FFFF) * H + q * 4);
    ushort4 r0 = *(const ushort4*)(relb + (size_t)(e0 >> 17) * H + q * 4);
    ushort4 h1 = *(const ushort4*)(hb + (size_t)(e1 & 0x1FFFF) * H + q * 4);
    ushort4 r1 = *(const ushort4*)(relb + (size_t)(e1 >> 17) * H + q * 4);
    a0 += b2f(h0.x) + b2f(r0.x) + b2f(h1.x) + b2f(r1.x);
    a1 += b2f(h0.y) + b2f(r0.y) + b2f(h1.y) + b2f(r1.y);
    a2 += b2f(h0.z) + b2f(r0.z) + b2f(h1.z) + b2f(r1.z);
    a3 += b2f(h0.w) + b2f(r0.w) + b2f(h1.w) + b2f(r1.w);
  }
  if (i < end) {
    u32 e0 = edges[i];
    ushort4 h0 = *(const ushort4*)(hb + (size_t)(e0 & 0x1FFFF) * H + q * 4);
    ushort4 r0 = *(const ushort4*)(relb + (size_t)(e0 >> 17) * H + q * 4);
    a0 += b2f(h0.x) + b2f(r0.x); a1 += b2f(h0.y) + b2f(r0.y);
    a2 += b2f(h0.z) + b2f(r0.z); a3 += b2f(h0.w) + b2f(r0.w);
  }
  int deg = end - start;
  float nm = 1.0f / (float)(deg > 0 ? deg : 1);
  ushort4 o;
  o.x = f2b(a0 * nm); o.y = f2b(a1 * nm);
  o.z = f2b(a2 * nm); o.w = f2b(a3 * nm);
  *(ushort4*)(aggb + (size_t)d * H + q * 4) = o;
}

// ---------- layer-0: hA = rrelu(agg@Wn0 + h@Wl0), bf16 out ----------
__global__ __launch_bounds__(256) void rgcn_gemm0(
    const u16* __restrict__ A1, const u16* __restrict__ A2,
    const u16* __restrict__ B1t, const u16* __restrict__ B2t, u16* __restrict__ Cb) {
  int wave = threadIdx.x >> 6, lane = threadIdx.x & 63;
  int row0 = blockIdx.x * 64 + wave * 16;
  int ar = lane & 15, kg = lane >> 4;
  int arow = row0 + ar;
  if (arow >= N_ENT) arow = N_ENT - 1;
  bf16x8 a1[4], a2[4];
#pragma unroll
  for (int s = 0; s < 4; s++) {
    a1[s] = *(const bf16x8*)(A1 + (size_t)arow * H + s * 32 + kg * 8);
    a2[s] = *(const bf16x8*)(A2 + (size_t)arow * H + s * 32 + kg * 8);
  }
  f32x4 acc[8];
  f32x4 z = {0.f, 0.f, 0.f, 0.f};
#pragma unroll
  for (int n = 0; n < 8; n++) acc[n] = z;
#pragma unroll
  for (int n = 0; n < 8; n++) {
    const u16* b1p = B1t + (size_t)(n * 16 + ar) * H + kg * 8;
    const u16* b2p = B2t + (size_t)(n * 16 + ar) * H + kg * 8;
#pragma unroll
    for (int s = 0; s < 4; s++) {
      bf16x8 b1 = *(const bf16x8*)(b1p + s * 32);
      bf16x8 b2 = *(const bf16x8*)(b2p + s * 32);
      acc[n] = __builtin_amdgcn_mfma_f32_16x16x32_bf16(a1[s], b1, acc[n], 0, 0, 0);
      acc[n] = __builtin_amdgcn_mfma_f32_16x16x32_bf16(a2[s], b2, acc[n], 0, 0, 0);
    }
  }
#pragma unroll
  for (int n = 0; n < 8; n++) {
    int c = ar + n * 16;
#pragma unroll
    for (int r = 0; r < 4; r++) {
      int gr = row0 + kg * 4 + r;
      if (gr < N_ENT) {
        float v = acc[n][r];
        v = v >= 0.f ? v : SLOPE * v;
        Cb[(size_t)gr * H + c] = f2b(v);
      }
    }
  }
}

// ---------- fused layer-1 GEMM + gate GEMM + rrelu + l2norm + combine ----------
// h_n(f32) = g*l2norm(rrelu(agg@Wn1 + hA@Wl1)) + (1-g)*h_t, g=sigmoid(h_t@Tg+b)
// also writes bf16 state hb (in-place over its own gate input rows)
__global__ __launch_bounds__(256) void step_final(
    const u16* __restrict__ aggb, const u16* __restrict__ hAb, const u16* hbio,
    const u16* __restrict__ B1t, const u16* __restrict__ B2t, const u16* __restrict__ B3t,
    const float* __restrict__ tgb, const float* __restrict__ h_t, float* __restrict__ h_n,
    u16* hb_out) {
  int wave = threadIdx.x >> 6, lane = threadIdx.x & 63;
  int row0 = blockIdx.x * 64 + wave * 16;
  int ar = lane & 15, kg = lane >> 4;
  int arow = row0 + ar;
  if (arow >= N_ENT) arow = N_ENT - 1;
  bf16x8 a1[4], a2[4], a3[4];
#pragma unroll
  for (int s = 0; s < 4; s++) {
    a1[s] = *(const bf16x8*)(aggb + (size_t)arow * H + s * 32 + kg * 8);
    a2[s] = *(const bf16x8*)(hAb + (size_t)arow * H + s * 32 + kg * 8);
    a3[s] = *(const bf16x8*)(hbio + (size_t)arow * H + s * 32 + kg * 8);
  }
  f32x4 accm[8], accg[8];
  f32x4 z4 = {0.f, 0.f, 0.f, 0.f};
#pragma unroll
  for (int n = 0; n < 8; n++) { accm[n] = z4; accg[n] = z4; }
#pragma unroll
  for (int n = 0; n < 8; n++) {
    const u16* b1p = B1t + (size_t)(n * 16 + ar) * H + kg * 8;
    const u16* b2p = B2t + (size_t)(n * 16 + ar) * H + kg * 8;
    const u16* b3p = B3t + (size_t)(n * 16 + ar) * H + kg * 8;
#pragma unroll
    for (int s = 0; s < 4; s++) {
      bf16x8 b1 = *(const bf16x8*)(b1p + s * 32);
      bf16x8 b2 = *(const bf16x8*)(b2p + s * 32);
      bf16x8 b3 = *(const bf16x8*)(b3p + s * 32);
      accm[n] = __builtin_amdgcn_mfma_f32_16x16x32_bf16(a1[s], b1, accm[n], 0, 0, 0);
      accm[n] = __builtin_amdgcn_mfma_f32_16x16x32_bf16(a2[s], b2, accm[n], 0, 0, 0);
      accg[n] = __builtin_amdgcn_mfma_f32_16x16x32_bf16(a3[s], b3, accg[n], 0, 0, 0);
    }
  }
#pragma unroll
  for (int r = 0; r < 4; r++) {
    int grow = row0 + kg * 4 + r;
    bool ok = grow < N_ENT;
    float zs[8], ssq = 0.f;
#pragma unroll
    for (int n = 0; n < 8; n++) {
      float v = accm[n][r];
      v = v >= 0.f ? v : SLOPE * v;
      zs[n] = v;
      ssq += v * v;
    }
    ssq += __shfl_xor(ssq, 1, 64);
    ssq += __shfl_xor(ssq, 2, 64);
    ssq += __shfl_xor(ssq, 4, 64);
    ssq += __shfl_xor(ssq, 8, 64);
    float inv = 1.0f / fmaxf(sqrtf(ssq), 1e-12f);
#pragma unroll
    for (int n = 0; n < 8; n++) {
      int c = ar + n * 16;
      float g = 1.0f / (1.0f + expf(-(accg[n][r] + tgb[c])));
      float hp = ok ? h_t[(size_t)grow * H + c] : 0.f;
      float o = g * (zs[n] * inv) + (1.0f - g) * hp;
      if (ok) {
        h_n[(size_t)grow * H + c] = o;
        hb_out[(size_t)grow * H + c] = f2b(o);
      }
    }
  }
}

// ---------- deg==0 fixups (expected ~0.3 rows) ----------
__global__ void fixup0_kernel(const u16* __restrict__ hb, const float* __restrict__ We,
                              const int* __restrict__ rp, u16* __restrict__ hA) {
  for (int r = blockIdx.x; r < N_ENT; r += gridDim.x) {
    int start = r ? rp[r - 1] : 0;
    if (rp[r] > start) continue;
    int c = threadIdx.x;  // 128
    float s = 0.f;
    for (int k = 0; k < H; k++) s += b2f(hb[(size_t)r * H + k]) * We[(size_t)k * H + c];
    s = s >= 0.f ? s : SLOPE * s;
    hA[(size_t)r * H + c] = f2b(s);
  }
}

// redo full layer1+gate+combine for deg==0 rows (f32 weights)
__global__ void fixup1_kernel(const u16* __restrict__ hAb, const float* __restrict__ We,
                              const float* __restrict__ tgw, const float* __restrict__ tgb,
                              const float* __restrict__ h_t, const int* __restrict__ rp,
                              float* __restrict__ h_n, u16* __restrict__ hb) {
  __shared__ float red[2];
  for (int r = blockIdx.x; r < N_ENT; r += gridDim.x) {
    int start = r ? rp[r - 1] : 0;
    if (rp[r] > start) continue;
    int c = threadIdx.x;  // 128
    float zv = 0.f, gv = 0.f;
    for (int k = 0; k < H; k++) {
      float ha = b2f(hAb[(size_t)r * H + k]);
      float ht = h_t[(size_t)r * H + k];
      zv += ha * We[(size_t)k * H + c];
      gv += ht * tgw[(size_t)k * H + c];
    }
    zv = zv >= 0.f ? zv : SLOPE * zv;
    gv = 1.0f / (1.0f + expf(-(gv + tgb[c])));
    float ssq = wave_sum(zv * zv);
    if ((threadIdx.x & 63) == 0) red[threadIdx.x >> 6] = ssq;
    __syncthreads();
    float inv = 1.0f / fmaxf(sqrtf(red[0] + red[1]), 1e-12f);
    float hp = h_t[(size_t)r * H + c];
    float o = gv * (zv * inv) + (1.0f - gv) * hp;
    h_n[(size_t)r * H + c] = o;
    hb[(size_t)r * H + c] = f2b(o);
    __syncthreads();
  }
}

extern "C" void kernel_launch(void* const* d_in, const int* in_sizes, int n_in,
                              void* d_out, int out_size, void* d_ws, size_t ws_size,
                              hipStream_t stream) {
  const float* emb_ent  = (const float*)d_in[0];
  const float* emb_rel  = (const float*)d_in[1];
  const float* w_neigh  = (const float*)d_in[2];
  const float* w_loop   = (const float*)d_in[3];
  const float* w_evolve = (const float*)d_in[4];
  const float* tg_w     = (const float*)d_in[5];
  const float* tg_b     = (const float*)d_in[6];
  const int* src = (const int*)d_in[7];
  const int* dst = (const int*)d_in[8];
  const int* ety = (const int*)d_in[9];
  float* out = (float*)d_out;

  const size_t NH = (size_t)N_ENT * H;
  auto au = [](size_t x) { return (x + 255) & ~(size_t)255; };
  char* w = (char*)d_ws;
  int* rp8 = (int*)w;     w += au((size_t)T_STEPS * N_ENT * 4);
  int* bcnt = (int*)w;    w += au((size_t)T_STEPS * NBUK * 4);
  int* bstart = (int*)w;  w += au((size_t)T_STEPS * NBUK * 4);
  int* curA = (int*)w;    w += au((size_t)T_STEPS * NBUK * 4);
  u64* tmp = (u64*)w;     w += au((size_t)NEDGE * 8);
  u32* edges8 = (u32*)w;  w += au((size_t)T_STEPS * NEDGE * 4);
  u16* aggb = (u16*)w;    w += au(NH * 2);
  u16* hAb = (u16*)w;     w += au(NH * 2);
  u16* hb = (u16*)w;      w += au(NH * 2);
  u16* wbt = (u16*)w;     w += au((size_t)5 * 16384 * 2);
  u16* relb = (u16*)w;    w += au((size_t)NREL * H * 2);

  // emb_rel passthrough + weight conversions + h0
  hipMemcpyAsync(out + (size_t)(T_STEPS + 1) * NH, emb_rel, (size_t)NREL * H * 4,
                 hipMemcpyDeviceToDevice, stream);
  convw_kernel<<<320, 256, 0, stream>>>(w_neigh, w_loop, tg_w, wbt);
  convrel_kernel<<<230, 256, 0, stream>>>(emb_rel, relb);
  l2norm_kernel<<<N_ENT / 4, 256, 0, stream>>>(emb_ent, out, hb);

  // bucketed CSR build
  hipMemsetAsync(bcnt, 0, (size_t)T_STEPS * NBUK * 4, stream);
  bucket_count<<<dim3(64, T_STEPS), 256, 0, stream>>>(dst, bcnt);
  bucket_scan<<<T_STEPS, 512, 0, stream>>>(bcnt, bstart, curA);
  for (int t = 0; t < T_STEPS; t++) {
    passA_kernel<<<(NEDGE + 255) / 256, 256, 0, stream>>>(src, dst, ety, curA, tmp, t);
    passB_kernel<<<NBUK, 256, 0, stream>>>(tmp, bstart, rp8, edges8, t);
  }

  for (int t = 0; t < T_STEPS; t++) {
    float* h_t = out + (size_t)t * NH;
    float* h_n = out + (size_t)(t + 1) * NH;
    const int* rp = rp8 + (size_t)t * N_ENT;
    const u32* edges = edges8 + (size_t)t * NEDGE;

    // layer 0
    gather_kernel<<<N_ENT / 8, 256, 0, stream>>>(hb, relb, rp, edges, aggb);
    rgcn_gemm0<<<(N_ENT + 63) / 64, 256, 0, stream>>>(aggb, hb, wbt, wbt + 16384, hAb);
    fixup0_kernel<<<256, 128, 0, stream>>>(hb, w_evolve, rp, hAb);
    // layer 1 + gate + l2norm + combine (fused)
    gather_kernel<<<N_ENT / 8, 256, 0, stream>>>(hAb, relb, rp, edges, aggb);
    step_final<<<(N_ENT + 63) / 64, 256, 0, stream>>>(
        aggb, hAb, hb, wbt + 32768, wbt + 49152, wbt + 65536, tg_b, h_t, h_n, hb);
    fixup1_kernel<<<256, 128, 0, stream>>>(hAb, w_evolve + 16384, tg_w, tg_b, h_t, rp,
                                           h_n, hb);
  }
}

// Round 5
// 2242.429 us; speedup vs baseline: 1.7467x; 1.7467x over previous
//
#include <hip/hip_runtime.h>

#define N_ENT 50000
#define H 128
#define NREL 460
#define T_STEPS 8
#define NEDGE 600000
#define SLOPE 0.22916666666666666f
#define NBUK 391   // ceil(N_ENT/128)
#define EPB 4096   // edges per passA block

typedef __attribute__((ext_vector_type(8))) short bf16x8;
typedef __attribute__((ext_vector_type(4))) float f32x4;
typedef unsigned short u16;
typedef unsigned int u32;
typedef unsigned long long u64;

__device__ __forceinline__ float b2f(u16 u) {
  union { u32 i; float f; } v; v.i = ((u32)u) << 16; return v.f;
}
__device__ __forceinline__ u16 f2b(float f) {
  union { float f; u32 i; } v; v.f = f;
  return (u16)((v.i + 0x7FFFu + ((v.i >> 16) & 1u)) >> 16);
}
__device__ __forceinline__ float wave_sum(float v) {
#pragma unroll
  for (int off = 32; off > 0; off >>= 1) v += __shfl_xor(v, off, 64);
  return v;
}

// ---------- weight prep: bf16 transposed [n][k], 5 matrices ----------
__global__ void convw_kernel(const float* __restrict__ wn, const float* __restrict__ wl,
                             const float* __restrict__ tg, u16* __restrict__ wbt) {
  int m = blockIdx.x >> 6;
  int f = ((blockIdx.x & 63) << 8) + threadIdx.x;
  int n = f >> 7, k = f & 127;
  const float* src;
  switch (m) {
    case 0: src = wn; break;          // w_neigh[0]
    case 1: src = wl; break;          // w_loop[0]
    case 2: src = wn + 16384; break;  // w_neigh[1]
    case 3: src = wl + 16384; break;  // w_loop[1]
    default: src = tg; break;         // tg_w
  }
  wbt[m * 16384 + n * 128 + k] = f2b(src[k * 128 + n]);
}

// rel table f32 -> bf16
__global__ void convrel_kernel(const float* __restrict__ rel, u16* __restrict__ relb) {
  int i = blockIdx.x * 256 + threadIdx.x;  // 230*256 == 58880 exactly
  relb[i] = f2b(rel[i]);
}

// ---------- h0 = l2norm(emb_ent), f32 + bf16 ----------
__global__ void l2norm_kernel(const float* __restrict__ in, float* __restrict__ out,
                              u16* __restrict__ outb) {
  int row = blockIdx.x * 4 + (threadIdx.x >> 6);
  int lane = threadIdx.x & 63;
  size_t base = (size_t)row * H;
  float2 v = ((const float2*)(in + base))[lane];
  float ss = wave_sum(v.x * v.x + v.y * v.y);
  float inv = 1.0f / fmaxf(sqrtf(ss), 1e-12f);
  float2 o = {v.x * inv, v.y * inv};
  ((float2*)(out + base))[lane] = o;
  ushort2 ob; ob.x = f2b(o.x); ob.y = f2b(o.y);
  ((ushort2*)(outb + base))[lane] = ob;
}

// ---------- bucketed CSR build ----------
__global__ __launch_bounds__(256) void bucket_count(const int* __restrict__ dst,
                                                    int* __restrict__ bcnt) {
  int t = blockIdx.y;
  __shared__ int lc[NBUK];
  for (int j = threadIdx.x; j < NBUK; j += 256) lc[j] = 0;
  __syncthreads();
  for (int i = blockIdx.x * 256 + threadIdx.x; i < NEDGE; i += 64 * 256)
    atomicAdd(&lc[dst[(size_t)t * NEDGE + i] >> 7], 1);
  __syncthreads();
  for (int j = threadIdx.x; j < NBUK; j += 256)
    if (lc[j]) atomicAdd(&bcnt[t * NBUK + j], lc[j]);
}

__global__ __launch_bounds__(512) void bucket_scan(const int* __restrict__ bcnt,
                                                   int* __restrict__ bstart,
                                                   int* __restrict__ curA) {
  int t = blockIdx.x, tid = threadIdx.x;
  __shared__ int s[512];
  int v = (tid < NBUK) ? bcnt[t * NBUK + tid] : 0;
  s[tid] = v;
  __syncthreads();
  for (int off = 1; off < 512; off <<= 1) {
    int u = (tid >= off) ? s[tid - off] : 0;
    __syncthreads();
    s[tid] += u;
    __syncthreads();
  }
  if (tid < NBUK) {
    int ex = s[tid] - v;
    bstart[t * NBUK + tid] = ex;
    curA[t * NBUK + tid] = ex;
  }
}

// pass A (two-level): LDS bucket histogram -> chunked global reservation ->
// mostly-coalesced 8B scatter into reserved sub-ranges. All timesteps batched.
__global__ __launch_bounds__(256) void passA_kernel(const int* __restrict__ src,
                                                    const int* __restrict__ dst,
                                                    const int* __restrict__ ety,
                                                    int* curA, u64* __restrict__ tmp) {
  int t = blockIdx.y;
  __shared__ int cnt[NBUK], base[NBUK];
  for (int j = threadIdx.x; j < NBUK; j += 256) cnt[j] = 0;
  __syncthreads();
  int e0 = blockIdx.x * EPB;
  int e1 = e0 + EPB < NEDGE ? e0 + EPB : NEDGE;
  for (int i = e0 + threadIdx.x; i < e1; i += 256)
    atomicAdd(&cnt[dst[(size_t)t * NEDGE + i] >> 7], 1);
  __syncthreads();
  for (int j = threadIdx.x; j < NBUK; j += 256) {
    int c = cnt[j];
    base[j] = c ? atomicAdd(&curA[t * NBUK + j], c) : 0;
    cnt[j] = 0;  // becomes local cursor
  }
  __syncthreads();
  for (int i = e0 + threadIdx.x; i < e1; i += 256) {
    size_t o = (size_t)t * NEDGE + i;
    int d = dst[o];
    int j = d >> 7;
    int p = base[j] + atomicAdd(&cnt[j], 1);
    tmp[(size_t)t * NEDGE + p] = ((u64)d << 32) | (u32)src[o] | ((u32)ety[o] << 17);
  }
}

// pass B: one block per (bucket, t); per-dst counts+scan in LDS, write rp ends,
// scatter final 4B entries within the bucket's ~6KB window (L2-dense)
__global__ __launch_bounds__(256) void passB_kernel(const u64* __restrict__ tmp,
                                                    const int* __restrict__ bstart,
                                                    int* __restrict__ rp,
                                                    u32* __restrict__ edges) {
  int t = blockIdx.y, b = blockIdx.x, tid = threadIdx.x;
  int start = bstart[t * NBUK + b];
  int end = (b + 1 < NBUK) ? bstart[t * NBUK + b + 1] : NEDGE;
  __shared__ int cnt[128], scn[128], cur[128];
  if (tid < 128) cnt[tid] = 0;
  __syncthreads();
  for (int i = start + tid; i < end; i += 256)
    atomicAdd(&cnt[(int)((tmp[(size_t)t * NEDGE + i] >> 32) & 127)], 1);
  __syncthreads();
  if (tid < 128) scn[tid] = cnt[tid];
  __syncthreads();
  for (int off = 1; off < 128; off <<= 1) {
    int u = (tid < 128 && tid >= off) ? scn[tid - off] : 0;
    __syncthreads();
    if (tid < 128) scn[tid] += u;
    __syncthreads();
  }
  if (tid < 128) {
    int rs = start + scn[tid] - cnt[tid];
    cur[tid] = rs;
    int gd = (b << 7) + tid;
    if (gd < N_ENT) rp[t * N_ENT + gd] = rs + cnt[tid];  // end-of-row
  }
  __syncthreads();
  for (int i = start + tid; i < end; i += 256) {
    u64 e = tmp[(size_t)t * NEDGE + i];
    int p = atomicAdd(&cur[(int)((e >> 32) & 127)], 1);
    edges[(size_t)t * NEDGE + p] = (u32)e;
  }
}

// ---------- agg[d] = (sum h[src]+rel[ty]) / max(deg,1), bf16 in/out ----------
__global__ __launch_bounds__(256) void gather_kernel(const u16* __restrict__ hb,
                                                     const u16* __restrict__ relb,
                                                     const int* __restrict__ rp,
                                                     const u32* __restrict__ edges,
                                                     u16* __restrict__ aggb) {
  int d = blockIdx.x * 8 + (threadIdx.x >> 5);
  int q = threadIdx.x & 31;
  int start = d ? rp[d - 1] : 0, end = rp[d];
  float a0 = 0.f, a1 = 0.f, a2 = 0.f, a3 = 0.f;
  int i = start;
  for (; i + 4 <= end; i += 4) {
    u32 e0 = edges[i], e1 = edges[i + 1], e2 = edges[i + 2], e3 = edges[i + 3];
    ushort4 h0 = *(const ushort4*)(hb + (size_t)(e0 & 0x1FFFF) * H + q * 4);
    ushort4 r0 = *(const ushort4*)(relb + (size_t)(e0 >> 17) * H + q * 4);
    ushort4 h1 = *(const ushort4*)(hb + (size_t)(e1 & 0x1FFFF) * H + q * 4);
    ushort4 r1 = *(const ushort4*)(relb + (size_t)(e1 >> 17) * H + q * 4);
    ushort4 h2 = *(const ushort4*)(hb + (size_t)(e2 & 0x1FFFF) * H + q * 4);
    ushort4 r2 = *(const ushort4*)(relb + (size_t)(e2 >> 17) * H + q * 4);
    ushort4 h3 = *(const ushort4*)(hb + (size_t)(e3 & 0x1FFFF) * H + q * 4);
    ushort4 r3 = *(const ushort4*)(relb + (size_t)(e3 >> 17) * H + q * 4);
    a0 += (b2f(h0.x) + b2f(r0.x)) + (b2f(h1.x) + b2f(r1.x)) +
          (b2f(h2.x) + b2f(r2.x)) + (b2f(h3.x) + b2f(r3.x));
    a1 += (b2f(h0.y) + b2f(r0.y)) + (b2f(h1.y) + b2f(r1.y)) +
          (b2f(h2.y) + b2f(r2.y)) + (b2f(h3.y) + b2f(r3.y));
    a2 += (b2f(h0.z) + b2f(r0.z)) + (b2f(h1.z) + b2f(r1.z)) +
          (b2f(h2.z) + b2f(r2.z)) + (b2f(h3.z) + b2f(r3.z));
    a3 += (b2f(h0.w) + b2f(r0.w)) + (b2f(h1.w) + b2f(r1.w)) +
          (b2f(h2.w) + b2f(r2.w)) + (b2f(h3.w) + b2f(r3.w));
  }
  for (; i < end; i++) {
    u32 e0 = edges[i];
    ushort4 h0 = *(const ushort4*)(hb + (size_t)(e0 & 0x1FFFF) * H + q * 4);
    ushort4 r0 = *(const ushort4*)(relb + (size_t)(e0 >> 17) * H + q * 4);
    a0 += b2f(h0.x) + b2f(r0.x); a1 += b2f(h0.y) + b2f(r0.y);
    a2 += b2f(h0.z) + b2f(r0.z); a3 += b2f(h0.w) + b2f(r0.w);
  }
  int deg = end - start;
  float nm = 1.0f / (float)(deg > 0 ? deg : 1);
  ushort4 o;
  o.x = f2b(a0 * nm); o.y = f2b(a1 * nm);
  o.z = f2b(a2 * nm); o.w = f2b(a3 * nm);
  *(ushort4*)(aggb + (size_t)d * H + q * 4) = o;
}

// ---------- layer-0: hA = rrelu(agg@Wn0 + h@Wl0), bf16 out ----------
__global__ __launch_bounds__(256) void rgcn_gemm0(
    const u16* __restrict__ A1, const u16* __restrict__ A2,
    const u16* __restrict__ B1t, const u16* __restrict__ B2t, u16* __restrict__ Cb) {
  int wave = threadIdx.x >> 6, lane = threadIdx.x & 63;
  int row0 = blockIdx.x * 64 + wave * 16;
  int ar = lane & 15, kg = lane >> 4;
  int arow = row0 + ar;
  if (arow >= N_ENT) arow = N_ENT - 1;
  bf16x8 a1[4], a2[4];
#pragma unroll
  for (int s = 0; s < 4; s++) {
    a1[s] = *(const bf16x8*)(A1 + (size_t)arow * H + s * 32 + kg * 8);
    a2[s] = *(const bf16x8*)(A2 + (size_t)arow * H + s * 32 + kg * 8);
  }
  f32x4 acc[8];
  f32x4 z = {0.f, 0.f, 0.f, 0.f};
#pragma unroll
  for (int n = 0; n < 8; n++) acc[n] = z;
#pragma unroll
  for (int n = 0; n < 8; n++) {
    const u16* b1p = B1t + (size_t)(n * 16 + ar) * H + kg * 8;
    const u16* b2p = B2t + (size_t)(n * 16 + ar) * H + kg * 8;
#pragma unroll
    for (int s = 0; s < 4; s++) {
      bf16x8 b1 = *(const bf16x8*)(b1p + s * 32);
      bf16x8 b2 = *(const bf16x8*)(b2p + s * 32);
      acc[n] = __builtin_amdgcn_mfma_f32_16x16x32_bf16(a1[s], b1, acc[n], 0, 0, 0);
      acc[n] = __builtin_amdgcn_mfma_f32_16x16x32_bf16(a2[s], b2, acc[n], 0, 0, 0);
    }
  }
#pragma unroll
  for (int n = 0; n < 8; n++) {
    int c = ar + n * 16;
#pragma unroll
    for (int r = 0; r < 4; r++) {
      int gr = row0 + kg * 4 + r;
      if (gr < N_ENT) {
        float v = acc[n][r];
        v = v >= 0.f ? v : SLOPE * v;
        Cb[(size_t)gr * H + c] = f2b(v);
      }
    }
  }
}

// ---------- fused layer-1 GEMM + gate GEMM + rrelu + l2norm + combine ----------
__global__ __launch_bounds__(256) void step_final(
    const u16* __restrict__ aggb, const u16* __restrict__ hAb, const u16* hbio,
    const u16* __restrict__ B1t, const u16* __restrict__ B2t, const u16* __restrict__ B3t,
    const float* __restrict__ tgb, const float* __restrict__ h_t, float* __restrict__ h_n,
    u16* hb_out) {
  int wave = threadIdx.x >> 6, lane = threadIdx.x & 63;
  int row0 = blockIdx.x * 64 + wave * 16;
  int ar = lane & 15, kg = lane >> 4;
  int arow = row0 + ar;
  if (arow >= N_ENT) arow = N_ENT - 1;
  bf16x8 a1[4], a2[4], a3[4];
#pragma unroll
  for (int s = 0; s < 4; s++) {
    a1[s] = *(const bf16x8*)(aggb + (size_t)arow * H + s * 32 + kg * 8);
    a2[s] = *(const bf16x8*)(hAb + (size_t)arow * H + s * 32 + kg * 8);
    a3[s] = *(const bf16x8*)(hbio + (size_t)arow * H + s * 32 + kg * 8);
  }
  f32x4 accm[8], accg[8];
  f32x4 z4 = {0.f, 0.f, 0.f, 0.f};
#pragma unroll
  for (int n = 0; n < 8; n++) { accm[n] = z4; accg[n] = z4; }
#pragma unroll
  for (int n = 0; n < 8; n++) {
    const u16* b1p = B1t + (size_t)(n * 16 + ar) * H + kg * 8;
    const u16* b2p = B2t + (size_t)(n * 16 + ar) * H + kg * 8;
    const u16* b3p = B3t + (size_t)(n * 16 + ar) * H + kg * 8;
#pragma unroll
    for (int s = 0; s < 4; s++) {
      bf16x8 b1 = *(const bf16x8*)(b1p + s * 32);
      bf16x8 b2 = *(const bf16x8*)(b2p + s * 32);
      bf16x8 b3 = *(const bf16x8*)(b3p + s * 32);
      accm[n] = __builtin_amdgcn_mfma_f32_16x16x32_bf16(a1[s], b1, accm[n], 0, 0, 0);
      accm[n] = __builtin_amdgcn_mfma_f32_16x16x32_bf16(a2[s], b2, accm[n], 0, 0, 0);
      accg[n] = __builtin_amdgcn_mfma_f32_16x16x32_bf16(a3[s], b3, accg[n], 0, 0, 0);
    }
  }
#pragma unroll
  for (int r = 0; r < 4; r++) {
    int grow = row0 + kg * 4 + r;
    bool ok = grow < N_ENT;
    float zs[8], ssq = 0.f;
#pragma unroll
    for (int n = 0; n < 8; n++) {
      float v = accm[n][r];
      v = v >= 0.f ? v : SLOPE * v;
      zs[n] = v;
      ssq += v * v;
    }
    ssq += __shfl_xor(ssq, 1, 64);
    ssq += __shfl_xor(ssq, 2, 64);
    ssq += __shfl_xor(ssq, 4, 64);
    ssq += __shfl_xor(ssq, 8, 64);
    float inv = 1.0f / fmaxf(sqrtf(ssq), 1e-12f);
#pragma unroll
    for (int n = 0; n < 8; n++) {
      int c = ar + n * 16;
      float g = 1.0f / (1.0f + expf(-(accg[n][r] + tgb[c])));
      float hp = ok ? h_t[(size_t)grow * H + c] : 0.f;
      float o = g * (zs[n] * inv) + (1.0f - g) * hp;
      if (ok) {
        h_n[(size_t)grow * H + c] = o;
        hb_out[(size_t)grow * H + c] = f2b(o);
      }
    }
  }
}

// ---------- deg==0 fixups (expected ~0.3 rows) ----------
__global__ void fixup0_kernel(const u16* __restrict__ hb, const float* __restrict__ We,
                              const int* __restrict__ rp, u16* __restrict__ hA) {
  for (int r = blockIdx.x; r < N_ENT; r += gridDim.x) {
    int start = r ? rp[r - 1] : 0;
    if (rp[r] > start) continue;
    int c = threadIdx.x;  // 128
    float s = 0.f;
    for (int k = 0; k < H; k++) s += b2f(hb[(size_t)r * H + k]) * We[(size_t)k * H + c];
    s = s >= 0.f ? s : SLOPE * s;
    hA[(size_t)r * H + c] = f2b(s);
  }
}

__global__ void fixup1_kernel(const u16* __restrict__ hAb, const float* __restrict__ We,
                              const float* __restrict__ tgw, const float* __restrict__ tgb,
                              const float* __restrict__ h_t, const int* __restrict__ rp,
                              float* __restrict__ h_n, u16* __restrict__ hb) {
  __shared__ float red[2];
  for (int r = blockIdx.x; r < N_ENT; r += gridDim.x) {
    int start = r ? rp[r - 1] : 0;
    if (rp[r] > start) continue;
    int c = threadIdx.x;  // 128
    float zv = 0.f, gv = 0.f;
    for (int k = 0; k < H; k++) {
      float ha = b2f(hAb[(size_t)r * H + k]);
      float ht = h_t[(size_t)r * H + k];
      zv += ha * We[(size_t)k * H + c];
      gv += ht * tgw[(size_t)k * H + c];
    }
    zv = zv >= 0.f ? zv : SLOPE * zv;
    gv = 1.0f / (1.0f + expf(-(gv + tgb[c])));
    float ssq = wave_sum(zv * zv);
    if ((threadIdx.x & 63) == 0) red[threadIdx.x >> 6] = ssq;
    __syncthreads();
    float inv = 1.0f / fmaxf(sqrtf(red[0] + red[1]), 1e-12f);
    float hp = h_t[(size_t)r * H + c];
    float o = gv * (zv * inv) + (1.0f - gv) * hp;
    h_n[(size_t)r * H + c] = o;
    hb[(size_t)r * H + c] = f2b(o);
    __syncthreads();
  }
}

extern "C" void kernel_launch(void* const* d_in, const int* in_sizes, int n_in,
                              void* d_out, int out_size, void* d_ws, size_t ws_size,
                              hipStream_t stream) {
  const float* emb_ent  = (const float*)d_in[0];
  const float* emb_rel  = (const float*)d_in[1];
  const float* w_neigh  = (const float*)d_in[2];
  const float* w_loop   = (const float*)d_in[3];
  const float* w_evolve = (const float*)d_in[4];
  const float* tg_w     = (const float*)d_in[5];
  const float* tg_b     = (const float*)d_in[6];
  const int* src = (const int*)d_in[7];
  const int* dst = (const int*)d_in[8];
  const int* ety = (const int*)d_in[9];
  float* out = (float*)d_out;

  const size_t NH = (size_t)N_ENT * H;
  auto au = [](size_t x) { return (x + 255) & ~(size_t)255; };
  char* w = (char*)d_ws;
  int* rp8 = (int*)w;     w += au((size_t)T_STEPS * N_ENT * 4);
  int* bcnt = (int*)w;    w += au((size_t)T_STEPS * NBUK * 4);
  int* bstart = (int*)w;  w += au((size_t)T_STEPS * NBUK * 4);
  int* curA = (int*)w;    w += au((size_t)T_STEPS * NBUK * 4);
  u32* edges8 = (u32*)w;  w += au((size_t)T_STEPS * NEDGE * 4);
  // union: tmp (8*NEDGE*8 = 38.4MB) aliases aggb|hAb|hb (3*NH*2 = 38.4MB).
  // CSR build (writes+reads tmp) fully precedes l2norm (first hb write).
  char* uni = w;          w += au((size_t)T_STEPS * NEDGE * 8);
  u64* tmp = (u64*)uni;
  u16* aggb = (u16*)uni;
  u16* hAb = (u16*)(uni + NH * 2);
  u16* hb  = (u16*)(uni + NH * 4);
  u16* wbt = (u16*)w;     w += au((size_t)5 * 16384 * 2);
  u16* relb = (u16*)w;    w += au((size_t)NREL * H * 2);

  // ---- CSR build first (uses tmp region before hb aliases it) ----
  hipMemsetAsync(bcnt, 0, (size_t)T_STEPS * NBUK * 4, stream);
  bucket_count<<<dim3(64, T_STEPS), 256, 0, stream>>>(dst, bcnt);
  bucket_scan<<<T_STEPS, 512, 0, stream>>>(bcnt, bstart, curA);
  passA_kernel<<<dim3((NEDGE + EPB - 1) / EPB, T_STEPS), 256, 0, stream>>>(
      src, dst, ety, curA, tmp);
  passB_kernel<<<dim3(NBUK, T_STEPS), 256, 0, stream>>>(tmp, bstart, rp8, edges8);

  // ---- conversions + h0 (hb now safe to write) ----
  hipMemcpyAsync(out + (size_t)(T_STEPS + 1) * NH, emb_rel, (size_t)NREL * H * 4,
                 hipMemcpyDeviceToDevice, stream);
  convw_kernel<<<320, 256, 0, stream>>>(w_neigh, w_loop, tg_w, wbt);
  convrel_kernel<<<230, 256, 0, stream>>>(emb_rel, relb);
  l2norm_kernel<<<N_ENT / 4, 256, 0, stream>>>(emb_ent, out, hb);

  for (int t = 0; t < T_STEPS; t++) {
    float* h_t = out + (size_t)t * NH;
    float* h_n = out + (size_t)(t + 1) * NH;
    const int* rp = rp8 + (size_t)t * N_ENT;
    const u32* edges = edges8 + (size_t)t * NEDGE;

    // layer 0
    gather_kernel<<<N_ENT / 8, 256, 0, stream>>>(hb, relb, rp, edges, aggb);
    rgcn_gemm0<<<(N_ENT + 63) / 64, 256, 0, stream>>>(aggb, hb, wbt, wbt + 16384, hAb);
    fixup0_kernel<<<256, 128, 0, stream>>>(hb, w_evolve, rp, hAb);
    // layer 1 + gate + l2norm + combine (fused)
    gather_kernel<<<N_ENT / 8, 256, 0, stream>>>(hAb, relb, rp, edges, aggb);
    step_final<<<(N_ENT + 63) / 64, 256, 0, stream>>>(
        aggb, hAb, hb, wbt + 32768, wbt + 49152, wbt + 65536, tg_b, h_t, h_n, hb);
    fixup1_kernel<<<256, 128, 0, stream>>>(hAb, w_evolve + 16384, tg_w, tg_b, h_t, rp,
                                           h_n, hb);
  }
}

// Round 6
// 1455.663 us; speedup vs baseline: 2.6908x; 1.5405x over previous
//
#include <hip/hip_runtime.h>

#define N_ENT 50000
#define H 128
#define NREL 460
#define T_STEPS 8
#define NEDGE 600000
#define SLOPE 0.22916666666666666f
#define NBUK 391   // ceil(N_ENT/128)
#define EPB 4096   // edges per passA block
#define ZCAP 8192  // deg-0 list capacity per timestep

typedef __attribute__((ext_vector_type(8))) short bf16x8;
typedef __attribute__((ext_vector_type(8))) unsigned short us8;
typedef __attribute__((ext_vector_type(4))) float f32x4;
typedef unsigned short u16;
typedef unsigned int u32;
typedef unsigned long long u64;

__device__ __forceinline__ float b2f(u16 u) {
  union { u32 i; float f; } v; v.i = ((u32)u) << 16; return v.f;
}
__device__ __forceinline__ u16 f2b(float f) {
  union { float f; u32 i; } v; v.f = f;
  return (u16)((v.i + 0x7FFFu + ((v.i >> 16) & 1u)) >> 16);
}
__device__ __forceinline__ float wave_sum(float v) {
#pragma unroll
  for (int off = 32; off > 0; off >>= 1) v += __shfl_xor(v, off, 64);
  return v;
}

// ---------- weight prep: bf16 transposed [n][k], 5 matrices ----------
__global__ void convw_kernel(const float* __restrict__ wn, const float* __restrict__ wl,
                             const float* __restrict__ tg, u16* __restrict__ wbt) {
  int m = blockIdx.x >> 6;
  int f = ((blockIdx.x & 63) << 8) + threadIdx.x;
  int n = f >> 7, k = f & 127;
  const float* src;
  switch (m) {
    case 0: src = wn; break;          // w_neigh[0]
    case 1: src = wl; break;          // w_loop[0]
    case 2: src = wn + 16384; break;  // w_neigh[1]
    case 3: src = wl + 16384; break;  // w_loop[1]
    default: src = tg; break;         // tg_w
  }
  wbt[m * 16384 + n * 128 + k] = f2b(src[k * 128 + n]);
}

// rel table f32 -> bf16
__global__ void convrel_kernel(const float* __restrict__ rel, u16* __restrict__ relb) {
  int i = blockIdx.x * 256 + threadIdx.x;  // 230*256 == 58880 exactly
  relb[i] = f2b(rel[i]);
}

// ---------- h0 = l2norm(emb_ent), f32 + bf16 ----------
__global__ void l2norm_kernel(const float* __restrict__ in, float* __restrict__ out,
                              u16* __restrict__ outb) {
  int row = blockIdx.x * 4 + (threadIdx.x >> 6);
  int lane = threadIdx.x & 63;
  size_t base = (size_t)row * H;
  float2 v = ((const float2*)(in + base))[lane];
  float ss = wave_sum(v.x * v.x + v.y * v.y);
  float inv = 1.0f / fmaxf(sqrtf(ss), 1e-12f);
  float2 o = {v.x * inv, v.y * inv};
  ((float2*)(out + base))[lane] = o;
  ushort2 ob; ob.x = f2b(o.x); ob.y = f2b(o.y);
  ((ushort2*)(outb + base))[lane] = ob;
}

// ---------- bucketed CSR build ----------
__global__ __launch_bounds__(256) void bucket_count(const int* __restrict__ dst,
                                                    int* __restrict__ bcnt) {
  int t = blockIdx.y;
  __shared__ int lc[NBUK];
  for (int j = threadIdx.x; j < NBUK; j += 256) lc[j] = 0;
  __syncthreads();
  for (int i = blockIdx.x * 256 + threadIdx.x; i < NEDGE; i += 64 * 256)
    atomicAdd(&lc[dst[(size_t)t * NEDGE + i] >> 7], 1);
  __syncthreads();
  for (int j = threadIdx.x; j < NBUK; j += 256)
    if (lc[j]) atomicAdd(&bcnt[t * NBUK + j], lc[j]);
}

__global__ __launch_bounds__(512) void bucket_scan(const int* __restrict__ bcnt,
                                                   int* __restrict__ bstart,
                                                   int* __restrict__ curA,
                                                   int* __restrict__ zcnt) {
  int t = blockIdx.x, tid = threadIdx.x;
  if (tid == 0) zcnt[t] = 0;
  __shared__ int s[512];
  int v = (tid < NBUK) ? bcnt[t * NBUK + tid] : 0;
  s[tid] = v;
  __syncthreads();
  for (int off = 1; off < 512; off <<= 1) {
    int u = (tid >= off) ? s[tid - off] : 0;
    __syncthreads();
    s[tid] += u;
    __syncthreads();
  }
  if (tid < NBUK) {
    int ex = s[tid] - v;
    bstart[t * NBUK + tid] = ex;
    curA[t * NBUK + tid] = ex;
  }
}

// pass A (two-level): LDS bucket histogram -> chunked global reservation ->
// mostly-coalesced 8B scatter into reserved sub-ranges. All timesteps batched.
__global__ __launch_bounds__(256) void passA_kernel(const int* __restrict__ src,
                                                    const int* __restrict__ dst,
                                                    const int* __restrict__ ety,
                                                    int* curA, u64* __restrict__ tmp) {
  int t = blockIdx.y;
  __shared__ int cnt[NBUK], base[NBUK];
  for (int j = threadIdx.x; j < NBUK; j += 256) cnt[j] = 0;
  __syncthreads();
  int e0 = blockIdx.x * EPB;
  int e1 = e0 + EPB < NEDGE ? e0 + EPB : NEDGE;
  for (int i = e0 + threadIdx.x; i < e1; i += 256)
    atomicAdd(&cnt[dst[(size_t)t * NEDGE + i] >> 7], 1);
  __syncthreads();
  for (int j = threadIdx.x; j < NBUK; j += 256) {
    int c = cnt[j];
    base[j] = c ? atomicAdd(&curA[t * NBUK + j], c) : 0;
    cnt[j] = 0;  // becomes local cursor
  }
  __syncthreads();
  for (int i = e0 + threadIdx.x; i < e1; i += 256) {
    size_t o = (size_t)t * NEDGE + i;
    int d = dst[o];
    int j = d >> 7;
    int p = base[j] + atomicAdd(&cnt[j], 1);
    tmp[(size_t)t * NEDGE + p] = ((u64)d << 32) | (u32)src[o] | ((u32)ety[o] << 17);
  }
}

// pass B: one block per (bucket, t); per-dst counts+scan in LDS, write rp ends,
// scatter final 4B entries, and append deg-0 dsts to zlist
__global__ __launch_bounds__(256) void passB_kernel(const u64* __restrict__ tmp,
                                                    const int* __restrict__ bstart,
                                                    int* __restrict__ rp,
                                                    u32* __restrict__ edges,
                                                    int* __restrict__ zcnt,
                                                    int* __restrict__ zlist) {
  int t = blockIdx.y, b = blockIdx.x, tid = threadIdx.x;
  int start = bstart[t * NBUK + b];
  int end = (b + 1 < NBUK) ? bstart[t * NBUK + b + 1] : NEDGE;
  __shared__ int cnt[128], scn[128], cur[128];
  if (tid < 128) cnt[tid] = 0;
  __syncthreads();
  for (int i = start + tid; i < end; i += 256)
    atomicAdd(&cnt[(int)((tmp[(size_t)t * NEDGE + i] >> 32) & 127)], 1);
  __syncthreads();
  if (tid < 128) scn[tid] = cnt[tid];
  __syncthreads();
  for (int off = 1; off < 128; off <<= 1) {
    int u = (tid < 128 && tid >= off) ? scn[tid - off] : 0;
    __syncthreads();
    if (tid < 128) scn[tid] += u;
    __syncthreads();
  }
  if (tid < 128) {
    int rs = start + scn[tid] - cnt[tid];
    cur[tid] = rs;
    int gd = (b << 7) + tid;
    if (gd < N_ENT) {
      rp[t * N_ENT + gd] = rs + cnt[tid];  // end-of-row
      if (cnt[tid] == 0) {
        int p = atomicAdd(&zcnt[t], 1);
        if (p < ZCAP) zlist[t * ZCAP + p] = gd;
      }
    }
  }
  __syncthreads();
  for (int i = start + tid; i < end; i += 256) {
    u64 e = tmp[(size_t)t * NEDGE + i];
    int p = atomicAdd(&cur[(int)((e >> 32) & 127)], 1);
    edges[(size_t)t * NEDGE + p] = (u32)e;
  }
}

// ---------- agg[d] = (sum h[src]+rel[ty]) / max(deg,1), bf16 in/out ----------
// 16 lanes x ushort8 per row: 4 rows per wave, 8 outstanding 16B loads per lane
__global__ __launch_bounds__(256) void gather_kernel(const u16* __restrict__ hb,
                                                     const u16* __restrict__ relb,
                                                     const int* __restrict__ rp,
                                                     const u32* __restrict__ edges,
                                                     u16* __restrict__ aggb) {
  int d = blockIdx.x * 16 + (threadIdx.x >> 4);
  int q = threadIdx.x & 15;
  int start = d ? rp[d - 1] : 0, end = rp[d];
  float a[8] = {};
  int i = start;
  for (; i + 4 <= end; i += 4) {
    u32 e0 = edges[i], e1 = edges[i + 1], e2 = edges[i + 2], e3 = edges[i + 3];
    us8 h0 = *(const us8*)(hb + (size_t)(e0 & 0x1FFFF) * H + q * 8);
    us8 r0 = *(const us8*)(relb + (size_t)(e0 >> 17) * H + q * 8);
    us8 h1 = *(const us8*)(hb + (size_t)(e1 & 0x1FFFF) * H + q * 8);
    us8 r1 = *(const us8*)(relb + (size_t)(e1 >> 17) * H + q * 8);
    us8 h2 = *(const us8*)(hb + (size_t)(e2 & 0x1FFFF) * H + q * 8);
    us8 r2 = *(const us8*)(relb + (size_t)(e2 >> 17) * H + q * 8);
    us8 h3 = *(const us8*)(hb + (size_t)(e3 & 0x1FFFF) * H + q * 8);
    us8 r3 = *(const us8*)(relb + (size_t)(e3 >> 17) * H + q * 8);
#pragma unroll
    for (int j = 0; j < 8; j++)
      a[j] += (b2f(h0[j]) + b2f(r0[j])) + (b2f(h1[j]) + b2f(r1[j])) +
              (b2f(h2[j]) + b2f(r2[j])) + (b2f(h3[j]) + b2f(r3[j]));
  }
  for (; i < end; i++) {
    u32 e0 = edges[i];
    us8 h0 = *(const us8*)(hb + (size_t)(e0 & 0x1FFFF) * H + q * 8);
    us8 r0 = *(const us8*)(relb + (size_t)(e0 >> 17) * H + q * 8);
#pragma unroll
    for (int j = 0; j < 8; j++) a[j] += b2f(h0[j]) + b2f(r0[j]);
  }
  int deg = end - start;
  float nm = 1.0f / (float)(deg > 0 ? deg : 1);
  us8 o;
#pragma unroll
  for (int j = 0; j < 8; j++) o[j] = f2b(a[j] * nm);
  *(us8*)(aggb + (size_t)d * H + q * 8) = o;
}

// ---------- layer-0: hA = rrelu(agg@Wn0 + h@Wl0), bf16 out ----------
__global__ __launch_bounds__(256) void rgcn_gemm0(
    const u16* __restrict__ A1, const u16* __restrict__ A2,
    const u16* __restrict__ B1t, const u16* __restrict__ B2t, u16* __restrict__ Cb) {
  int wave = threadIdx.x >> 6, lane = threadIdx.x & 63;
  int row0 = blockIdx.x * 64 + wave * 16;
  int ar = lane & 15, kg = lane >> 4;
  int arow = row0 + ar;
  if (arow >= N_ENT) arow = N_ENT - 1;
  bf16x8 a1[4], a2[4];
#pragma unroll
  for (int s = 0; s < 4; s++) {
    a1[s] = *(const bf16x8*)(A1 + (size_t)arow * H + s * 32 + kg * 8);
    a2[s] = *(const bf16x8*)(A2 + (size_t)arow * H + s * 32 + kg * 8);
  }
  f32x4 acc[8];
  f32x4 z = {0.f, 0.f, 0.f, 0.f};
#pragma unroll
  for (int n = 0; n < 8; n++) acc[n] = z;
#pragma unroll
  for (int n = 0; n < 8; n++) {
    const u16* b1p = B1t + (size_t)(n * 16 + ar) * H + kg * 8;
    const u16* b2p = B2t + (size_t)(n * 16 + ar) * H + kg * 8;
#pragma unroll
    for (int s = 0; s < 4; s++) {
      bf16x8 b1 = *(const bf16x8*)(b1p + s * 32);
      bf16x8 b2 = *(const bf16x8*)(b2p + s * 32);
      acc[n] = __builtin_amdgcn_mfma_f32_16x16x32_bf16(a1[s], b1, acc[n], 0, 0, 0);
      acc[n] = __builtin_amdgcn_mfma_f32_16x16x32_bf16(a2[s], b2, acc[n], 0, 0, 0);
    }
  }
#pragma unroll
  for (int n = 0; n < 8; n++) {
    int c = ar + n * 16;
#pragma unroll
    for (int r = 0; r < 4; r++) {
      int gr = row0 + kg * 4 + r;
      if (gr < N_ENT) {
        float v = acc[n][r];
        v = v >= 0.f ? v : SLOPE * v;
        Cb[(size_t)gr * H + c] = f2b(v);
      }
    }
  }
}

// ---------- fused layer-1 GEMM + gate GEMM + rrelu + l2norm + combine ----------
__global__ __launch_bounds__(256) void step_final(
    const u16* __restrict__ aggb, const u16* __restrict__ hAb, const u16* hbio,
    const u16* __restrict__ B1t, const u16* __restrict__ B2t, const u16* __restrict__ B3t,
    const float* __restrict__ tgb, const float* __restrict__ h_t, float* __restrict__ h_n,
    u16* hb_out) {
  int wave = threadIdx.x >> 6, lane = threadIdx.x & 63;
  int row0 = blockIdx.x * 64 + wave * 16;
  int ar = lane & 15, kg = lane >> 4;
  int arow = row0 + ar;
  if (arow >= N_ENT) arow = N_ENT - 1;
  bf16x8 a1[4], a2[4], a3[4];
#pragma unroll
  for (int s = 0; s < 4; s++) {
    a1[s] = *(const bf16x8*)(aggb + (size_t)arow * H + s * 32 + kg * 8);
    a2[s] = *(const bf16x8*)(hAb + (size_t)arow * H + s * 32 + kg * 8);
    a3[s] = *(const bf16x8*)(hbio + (size_t)arow * H + s * 32 + kg * 8);
  }
  f32x4 accm[8], accg[8];
  f32x4 z4 = {0.f, 0.f, 0.f, 0.f};
#pragma unroll
  for (int n = 0; n < 8; n++) { accm[n] = z4; accg[n] = z4; }
#pragma unroll
  for (int n = 0; n < 8; n++) {
    const u16* b1p = B1t + (size_t)(n * 16 + ar) * H + kg * 8;
    const u16* b2p = B2t + (size_t)(n * 16 + ar) * H + kg * 8;
    const u16* b3p = B3t + (size_t)(n * 16 + ar) * H + kg * 8;
#pragma unroll
    for (int s = 0; s < 4; s++) {
      bf16x8 b1 = *(const bf16x8*)(b1p + s * 32);
      bf16x8 b2 = *(const bf16x8*)(b2p + s * 32);
      bf16x8 b3 = *(const bf16x8*)(b3p + s * 32);
      accm[n] = __builtin_amdgcn_mfma_f32_16x16x32_bf16(a1[s], b1, accm[n], 0, 0, 0);
      accm[n] = __builtin_amdgcn_mfma_f32_16x16x32_bf16(a2[s], b2, accm[n], 0, 0, 0);
      accg[n] = __builtin_amdgcn_mfma_f32_16x16x32_bf16(a3[s], b3, accg[n], 0, 0, 0);
    }
  }
#pragma unroll
  for (int r = 0; r < 4; r++) {
    int grow = row0 + kg * 4 + r;
    bool ok = grow < N_ENT;
    float zs[8], ssq = 0.f;
#pragma unroll
    for (int n = 0; n < 8; n++) {
      float v = accm[n][r];
      v = v >= 0.f ? v : SLOPE * v;
      zs[n] = v;
      ssq += v * v;
    }
    ssq += __shfl_xor(ssq, 1, 64);
    ssq += __shfl_xor(ssq, 2, 64);
    ssq += __shfl_xor(ssq, 4, 64);
    ssq += __shfl_xor(ssq, 8, 64);
    float inv = 1.0f / fmaxf(sqrtf(ssq), 1e-12f);
#pragma unroll
    for (int n = 0; n < 8; n++) {
      int c = ar + n * 16;
      float g = 1.0f / (1.0f + expf(-(accg[n][r] + tgb[c])));
      float hp = ok ? h_t[(size_t)grow * H + c] : 0.f;
      float o = g * (zs[n] * inv) + (1.0f - g) * hp;
      if (ok) {
        h_n[(size_t)grow * H + c] = o;
        hb_out[(size_t)grow * H + c] = f2b(o);
      }
    }
  }
}

// ---------- deg==0 fixups via zlist (expected ~0.3 rows/step) ----------
__global__ void fixup0_kernel(const u16* __restrict__ hb, const float* __restrict__ We,
                              const int* __restrict__ zcnt, const int* __restrict__ zlist,
                              u16* __restrict__ hA) {
  int n = *zcnt; if (n > ZCAP) n = ZCAP;
  for (int idx = blockIdx.x; idx < n; idx += gridDim.x) {
    int r = zlist[idx];
    int c = threadIdx.x;  // 128
    float s = 0.f;
    for (int k = 0; k < H; k++) s += b2f(hb[(size_t)r * H + k]) * We[(size_t)k * H + c];
    s = s >= 0.f ? s : SLOPE * s;
    hA[(size_t)r * H + c] = f2b(s);
  }
}

__global__ void fixup1_kernel(const u16* __restrict__ hAb, const float* __restrict__ We,
                              const float* __restrict__ tgw, const float* __restrict__ tgb,
                              const float* __restrict__ h_t, const int* __restrict__ zcnt,
                              const int* __restrict__ zlist,
                              float* __restrict__ h_n, u16* __restrict__ hb) {
  __shared__ float red[2];
  int n = *zcnt; if (n > ZCAP) n = ZCAP;
  for (int idx = blockIdx.x; idx < n; idx += gridDim.x) {
    int r = zlist[idx];
    int c = threadIdx.x;  // 128
    float zv = 0.f, gv = 0.f;
    for (int k = 0; k < H; k++) {
      float ha = b2f(hAb[(size_t)r * H + k]);
      float ht = h_t[(size_t)r * H + k];
      zv += ha * We[(size_t)k * H + c];
      gv += ht * tgw[(size_t)k * H + c];
    }
    zv = zv >= 0.f ? zv : SLOPE * zv;
    gv = 1.0f / (1.0f + expf(-(gv + tgb[c])));
    float ssq = wave_sum(zv * zv);
    if ((threadIdx.x & 63) == 0) red[threadIdx.x >> 6] = ssq;
    __syncthreads();
    float inv = 1.0f / fmaxf(sqrtf(red[0] + red[1]), 1e-12f);
    float hp = h_t[(size_t)r * H + c];
    float o = gv * (zv * inv) + (1.0f - gv) * hp;
    h_n[(size_t)r * H + c] = o;
    hb[(size_t)r * H + c] = f2b(o);
    __syncthreads();
  }
}

extern "C" void kernel_launch(void* const* d_in, const int* in_sizes, int n_in,
                              void* d_out, int out_size, void* d_ws, size_t ws_size,
                              hipStream_t stream) {
  const float* emb_ent  = (const float*)d_in[0];
  const float* emb_rel  = (const float*)d_in[1];
  const float* w_neigh  = (const float*)d_in[2];
  const float* w_loop   = (const float*)d_in[3];
  const float* w_evolve = (const float*)d_in[4];
  const float* tg_w     = (const float*)d_in[5];
  const float* tg_b     = (const float*)d_in[6];
  const int* src = (const int*)d_in[7];
  const int* dst = (const int*)d_in[8];
  const int* ety = (const int*)d_in[9];
  float* out = (float*)d_out;

  const size_t NH = (size_t)N_ENT * H;
  auto au = [](size_t x) { return (x + 255) & ~(size_t)255; };
  char* w = (char*)d_ws;
  int* rp8 = (int*)w;     w += au((size_t)T_STEPS * N_ENT * 4);
  int* bcnt = (int*)w;    w += au((size_t)T_STEPS * NBUK * 4);
  int* bstart = (int*)w;  w += au((size_t)T_STEPS * NBUK * 4);
  int* curA = (int*)w;    w += au((size_t)T_STEPS * NBUK * 4);
  int* zcnt = (int*)w;    w += au((size_t)T_STEPS * 4);
  int* zlist = (int*)w;   w += au((size_t)T_STEPS * ZCAP * 4);
  u32* edges8 = (u32*)w;  w += au((size_t)T_STEPS * NEDGE * 4);
  // union: tmp (8*NEDGE*8 = 38.4MB) aliases aggb|hAb|hb (3*NH*2 = 38.4MB).
  // CSR build (writes+reads tmp) fully precedes l2norm (first hb write).
  char* uni = w;          w += au((size_t)T_STEPS * NEDGE * 8);
  u64* tmp = (u64*)uni;
  u16* aggb = (u16*)uni;
  u16* hAb = (u16*)(uni + NH * 2);
  u16* hb  = (u16*)(uni + NH * 4);
  u16* wbt = (u16*)w;     w += au((size_t)5 * 16384 * 2);
  u16* relb = (u16*)w;    w += au((size_t)NREL * H * 2);

  // ---- CSR build first (uses tmp region before hb aliases it) ----
  hipMemsetAsync(bcnt, 0, (size_t)T_STEPS * NBUK * 4, stream);
  bucket_count<<<dim3(64, T_STEPS), 256, 0, stream>>>(dst, bcnt);
  bucket_scan<<<T_STEPS, 512, 0, stream>>>(bcnt, bstart, curA, zcnt);
  passA_kernel<<<dim3((NEDGE + EPB - 1) / EPB, T_STEPS), 256, 0, stream>>>(
      src, dst, ety, curA, tmp);
  passB_kernel<<<dim3(NBUK, T_STEPS), 256, 0, stream>>>(tmp, bstart, rp8, edges8,
                                                        zcnt, zlist);

  // ---- conversions + h0 (hb now safe to write) ----
  hipMemcpyAsync(out + (size_t)(T_STEPS + 1) * NH, emb_rel, (size_t)NREL * H * 4,
                 hipMemcpyDeviceToDevice, stream);
  convw_kernel<<<320, 256, 0, stream>>>(w_neigh, w_loop, tg_w, wbt);
  convrel_kernel<<<230, 256, 0, stream>>>(emb_rel, relb);
  l2norm_kernel<<<N_ENT / 4, 256, 0, stream>>>(emb_ent, out, hb);

  for (int t = 0; t < T_STEPS; t++) {
    float* h_t = out + (size_t)t * NH;
    float* h_n = out + (size_t)(t + 1) * NH;
    const int* rp = rp8 + (size_t)t * N_ENT;
    const u32* edges = edges8 + (size_t)t * NEDGE;
    const int* zc = zcnt + t;
    const int* zl = zlist + (size_t)t * ZCAP;

    // layer 0
    gather_kernel<<<N_ENT / 16, 256, 0, stream>>>(hb, relb, rp, edges, aggb);
    rgcn_gemm0<<<(N_ENT + 63) / 64, 256, 0, stream>>>(aggb, hb, wbt, wbt + 16384, hAb);
    fixup0_kernel<<<8, 128, 0, stream>>>(hb, w_evolve, zc, zl, hAb);
    // layer 1 + gate + l2norm + combine (fused)
    gather_kernel<<<N_ENT / 16, 256, 0, stream>>>(hAb, relb, rp, edges, aggb);
    step_final<<<(N_ENT + 63) / 64, 256, 0, stream>>>(
        aggb, hAb, hb, wbt + 32768, wbt + 49152, wbt + 65536, tg_b, h_t, h_n, hb);
    fixup1_kernel<<<8, 128, 0, stream>>>(hAb, w_evolve + 16384, tg_w, tg_b, h_t, zc, zl,
                                         h_n, hb);
  }
}